// Round 1
// baseline (115.758 us; speedup 1.0000x reference)
//
#include <hip/hip_runtime.h>

#define S_ROWS 524288
#define D_COLS 63
#define TILE_ROWS 128
#define TILE_ELEMS (TILE_ROWS * D_COLS)   // 8064
#define TILE_VEC4 (TILE_ELEMS / 4)        // 2016
#define BLOCK 256
#define GRID 512
#define NACC 30
#define POSW 0.2f

// gate flag bits
#define F_CUB  1u
#define F_CUB2 2u
#define F_AP   4u
#define F_REF  8u
#define F_TR   16u
#define F_SQ   32u

// accumulator indices (compile-time only)
enum {
  A_CMD_LOSS = 0, A_CMDC, A_MAE1, A_MAE2, A_MAE4, A_MAE5,
  A_CE_AP, A_CUBC,
  A_REF_AX_CE, A_REF_CUB_CE, A_REF_AXC, A_REF_CUBC,
  A_TR_AX_CE, A_TR_CUB_CE, A_TR_AXC, A_TR_CUBC,
  A_SQ_CUB_CE, A_FACE_CE, A_SQ_CUBC, A_FACEC,
  A_BCE, A_NPOS, A_NNEG, A_POSC, A_NEGC,
  A_NA, A_NC, A_NREF, A_NTR, A_NSQ
};

__device__ __forceinline__ float logsig(float x) {
  // log_sigmoid(x) = min(x,0) - log1p(exp(-|x|)), stable
  float ax = fabsf(x);
  return fminf(x, 0.f) - __logf(1.f + __expf(-ax));
}

__device__ __forceinline__ void slice_stats(const float* __restrict__ pr,
                                            const float* __restrict__ tr,
                                            int a, int b,
                                            int& targ, int& parg,
                                            float& lse, float& p_at_t) {
  float tmax = tr[a]; int ti = a;
  float pmax = pr[a]; int pi = a;
  #pragma unroll
  for (int j = a + 1; j < b; ++j) {
    float tv = tr[j]; if (tv > tmax) { tmax = tv; ti = j; }
    float pv = pr[j]; if (pv > pmax) { pmax = pv; pi = j; }
  }
  float se = 0.f;
  #pragma unroll
  for (int j = a; j < b; ++j) se += __expf(pr[j] - pmax);
  lse = pmax + __logf(se);
  targ = ti - a;
  parg = pi - a;
  p_at_t = pr[ti];
}

__global__ void init_ws(float* ws) {
  int i = threadIdx.x;
  if (i < NACC) ws[i] = 0.f;
  unsigned* wu = (unsigned*)ws;
  if (i == NACC) wu[NACC] = 0xFFFFFFFFu;   // first cub row (atomicMin)
  if (i == NACC + 1) wu[NACC + 1] = 0u;    // gate flags (atomicOr)
}

__launch_bounds__(BLOCK, 2)
__global__ void prog_loss_main(const float* __restrict__ P,
                               const float* __restrict__ T,
                               const float* __restrict__ W,
                               float* __restrict__ ws) {
  __shared__ float sp[TILE_ELEMS];
  __shared__ float st[TILE_ELEMS];
  __shared__ int scmd[TILE_ROWS];
  __shared__ float sred[4][NACC];
  __shared__ unsigned sflags[4];
  __shared__ unsigned smin[4];

  const int tid = threadIdx.x;
  const int lane = tid & 63;
  const int wave = tid >> 6;

  float acc[NACC];
  #pragma unroll
  for (int v = 0; v < NACC; ++v) acc[v] = 0.f;
  unsigned fl = 0u;
  unsigned mymin = 0xFFFFFFFFu;

  const int n_tiles = S_ROWS / TILE_ROWS;
  for (int tile = blockIdx.x; tile < n_tiles; tile += gridDim.x) {
    const size_t base = (size_t)tile * TILE_ELEMS;
    // ---- stage P, T -> LDS (coalesced float4; tile base is 16B-aligned) ----
    {
      const float4* P4 = (const float4*)(P + base);
      const float4* T4 = (const float4*)(T + base);
      float4* sp4 = (float4*)sp;
      float4* st4 = (float4*)st;
      #pragma unroll
      for (int k = 0; k < 8; ++k) {
        int i = tid + k * BLOCK;
        if (i < TILE_VEC4) {
          float4 a = P4[i];
          float4 b = T4[i];
          sp4[i] = a;
          st4[i] = b;
        }
      }
    }
    __syncthreads();

    // ---- phase A: per-row slice stats (threads 0..127) ----
    if (tid < TILE_ROWS) {
      const float* pr = sp + tid * D_COLS;
      const float* tr = st + tid * D_COLS;
      const unsigned gr = (unsigned)(tile * TILE_ROWS + tid);

      int c, pc;   float lseA, pA; slice_stats(pr, tr, 0, 7,  c,  pc,  lseA, pA);
      int c1, pc1; float lseB, pB; slice_stats(pr, tr, 7, 18, c1, pc1, lseB, pB);
      int c2, pc2; float lseC, pC; slice_stats(pr, tr, 18, 29, c2, pc2, lseC, pC);
      int c3, pc3; float lseD, pD; slice_stats(pr, tr, 29, 40, c3, pc3, lseD, pD);
      int ax, pax; float lseE, pE; slice_stats(pr, tr, 49, 52, ax, pax, lseE, pE);
      int fc, pfc; float lseF, pF; slice_stats(pr, tr, 54, 60, fc, pfc, lseF, pF);
      float x62 = pr[62], t62 = tr[62];

      acc[A_CMD_LOSS] += lseA - pA;
      acc[A_CMDC] += (c == pc) ? 1.f : 0.f;
      scmd[tid] = c;

      if (c == 1) {
        acc[A_NC] += 1.f;
        float bce = -(POSW * t62 * logsig(x62) + (1.f - t62) * logsig(-x62));
        acc[A_BCE] += bce;
        bool pos = (t62 == 1.f), neg = (t62 == 0.f);
        acc[A_NPOS] += pos ? 1.f : 0.f;
        acc[A_NNEG] += neg ? 0.f : 0.f;  // placeholder, fixed below
        acc[A_NNEG] += neg ? 1.f : 0.f;
        acc[A_POSC] += (pos && x62 > 0.f) ? 1.f : 0.f;
        acc[A_NEGC] += (neg && x62 <= 0.f) ? 1.f : 0.f;
        if (gr >= 1u) fl |= F_CUB;
        if (gr >= 2u) fl |= F_CUB2;
        mymin = (gr < mymin) ? gr : mymin;
      } else if (c == 2) {
        acc[A_NA] += 1.f;
        acc[A_CUBC] += (pc1 == c1 && pc2 == c2) ? 1.f : 0.f;
        acc[A_CE_AP] += (lseB - pB) + (lseC - pC);
        if (gr >= 1u) fl |= F_AP;
      } else if (c == 3) {
        acc[A_NREF] += 1.f;
        acc[A_REF_AX_CE] += lseE - pE;
        acc[A_REF_CUB_CE] += lseB - pB;
        acc[A_REF_AXC] += (pax == ax) ? 1.f : 0.f;
        acc[A_REF_CUBC] += (pc1 == c1) ? 1.f : 0.f;
        if (gr >= 1u) fl |= F_REF;
      } else if (c == 4) {
        acc[A_NTR] += 1.f;
        acc[A_TR_AX_CE] += lseE - pE;
        acc[A_TR_CUB_CE] += lseB - pB;
        acc[A_TR_AXC] += (pax == ax) ? 1.f : 0.f;
        acc[A_TR_CUBC] += (pc1 == c1) ? 1.f : 0.f;
        if (gr >= 1u) fl |= F_TR;
      } else if (c == 5) {
        acc[A_NSQ] += 1.f;
        acc[A_SQ_CUBC] += (pc1 == c1 && pc2 == c2 && pc3 == c3) ? 1.f : 0.f;
        acc[A_FACEC] += (fc == pfc) ? 1.f : 0.f;
        acc[A_SQ_CUB_CE] += (lseB - pB) + (lseC - pC) + (lseD - pD);
        acc[A_FACE_CE] += lseF - pF;
        if (gr >= 1u) fl |= F_SQ;
      }
    }
    __syncthreads();

    // ---- phase B: masked MAE, coalesced W + LDS p,t ----
    {
      const float4* W4 = (const float4*)(W + base);
      const float4* sp4 = (const float4*)sp;
      const float4* st4 = (const float4*)st;
      #pragma unroll
      for (int k = 0; k < 8; ++k) {
        int i = tid + k * BLOCK;
        if (i < TILE_VEC4) {
          float4 w = W4[i];
          float4 p = sp4[i];
          float4 t = st4[i];
          int e = i * 4;
          float wv[4] = {w.x, w.y, w.z, w.w};
          float pv[4] = {p.x, p.y, p.z, p.w};
          float tv[4] = {t.x, t.y, t.z, t.w};
          #pragma unroll
          for (int q = 0; q < 4; ++q) {
            unsigned row = (unsigned)(e + q) / 63u;
            int c = scmd[row];
            float v = wv[q] * fabsf(pv[q] - tv[q]);
            acc[A_MAE1] += (c == 1) ? v : 0.f;
            acc[A_MAE2] += (c == 2) ? v : 0.f;
            acc[A_MAE4] += (c == 4) ? v : 0.f;
            acc[A_MAE5] += (c == 5) ? v : 0.f;
          }
        }
      }
    }
    __syncthreads();  // protect LDS before next tile's staging
  }

  // ---- reduction: wave shuffle -> LDS -> atomics ----
  #pragma unroll
  for (int v = 0; v < NACC; ++v) {
    float x = acc[v];
    #pragma unroll
    for (int off = 32; off > 0; off >>= 1) x += __shfl_down(x, off, 64);
    if (lane == 0) sred[wave][v] = x;
  }
  {
    unsigned f = fl, m = mymin;
    #pragma unroll
    for (int off = 32; off > 0; off >>= 1) {
      f |= __shfl_down(f, off, 64);
      unsigned om = __shfl_down(m, off, 64);
      m = (om < m) ? om : m;
    }
    if (lane == 0) { sflags[wave] = f; smin[wave] = m; }
  }
  __syncthreads();
  unsigned* wu = (unsigned*)ws;
  if (tid == 0) {
    unsigned f = sflags[0] | sflags[1] | sflags[2] | sflags[3];
    unsigned m = min(min(smin[0], smin[1]), min(smin[2], smin[3]));
    if (f) atomicOr(&wu[NACC + 1], f);
    if (m != 0xFFFFFFFFu) atomicMin(&wu[NACC], m);
  }
  if (tid < NACC) {
    float s = sred[0][tid] + sred[1][tid] + sred[2][tid] + sred[3][tid];
    atomicAdd(&ws[tid], s);
  }
}

__global__ void finalize_k(const float* __restrict__ ws,
                           const float* __restrict__ P,
                           const float* __restrict__ T,
                           float* __restrict__ out) {
  const unsigned* wu = (const unsigned*)ws;
  unsigned flags = wu[NACC + 1];
  unsigned fm = wu[NACC];
  bool g_cub  = (flags & F_CUB)  != 0;
  bool g_cub2 = (flags & F_CUB2) != 0;
  bool g_ap   = (flags & F_AP)   != 0;
  bool g_ref  = (flags & F_REF)  != 0;
  bool g_tr   = (flags & F_TR)   != 0;
  bool g_sq   = (flags & F_SQ)   != 0;
  unsigned first = (fm == 0xFFFFFFFFu) ? 0u : fm;
  float x62 = P[(size_t)first * D_COLS + 62];
  float t62 = T[(size_t)first * D_COLS + 62];
  float bce_f = -(POSW * t62 * logsig(x62) + (1.f - t62) * logsig(-x62));
  float pos_f  = (t62 == 1.f) ? 1.f : 0.f;
  float neg_f  = (t62 == 0.f) ? 1.f : 0.f;
  float posc_f = (t62 == 1.f && x62 > 0.f) ? 1.f : 0.f;
  float negc_f = (t62 == 0.f && x62 <= 0.f) ? 1.f : 0.f;

  out[0]  = ws[A_CMD_LOSS];
  out[1]  = g_cub ? ws[A_MAE1] : 0.f;
  out[2]  = g_ap  ? ws[A_MAE2] : 0.f;
  out[3]  = g_sq  ? ws[A_MAE5] : 0.f;
  out[4]  = g_tr  ? ws[A_MAE4] : 0.f;
  out[5]  = g_ap  ? ws[A_CE_AP] : 0.f;
  out[6]  = g_sq  ? ws[A_SQ_CUB_CE] : 0.f;
  out[7]  = (g_ref ? ws[A_REF_CUB_CE] : 0.f) + (g_tr ? ws[A_TR_CUB_CE] : 0.f);
  out[8]  = (g_ref ? ws[A_REF_AX_CE]  : 0.f) + (g_tr ? ws[A_TR_AX_CE]  : 0.f);
  out[9]  = g_sq ? ws[A_FACE_CE] : 0.f;
  out[10] = ws[A_CMDC];
  out[11] = g_ap ? ws[A_CUBC] : 0.f;
  out[12] = g_sq ? ws[A_SQ_CUBC] : 0.f;
  out[13] = (g_ref ? ws[A_REF_CUBC] : 0.f) + (g_tr ? ws[A_TR_CUBC] : 0.f);
  out[14] = (g_ref ? ws[A_REF_AXC]  : 0.f) + (g_tr ? ws[A_TR_AXC]  : 0.f);
  out[15] = g_sq ? ws[A_FACEC] : 0.f;
  out[16] = g_cub2 ? (ws[A_BCE]  - bce_f)  : 0.f;
  out[17] = g_cub2 ? (ws[A_POSC] - posc_f) : 0.f;
  out[18] = g_cub2 ? (ws[A_NEGC] - negc_f) : 0.f;
  out[19] = g_cub2 ? (ws[A_NNEG] - neg_f)  : 0.f;
  out[20] = g_cub2 ? (ws[A_NPOS] - pos_f)  : 0.f;
  out[21] = ws[A_NA];
  out[22] = ws[A_NC];
  out[23] = ws[A_NREF] + ws[A_NTR];
  out[24] = ws[A_NSQ];
}

extern "C" void kernel_launch(void* const* d_in, const int* in_sizes, int n_in,
                              void* d_out, int out_size, void* d_ws, size_t ws_size,
                              hipStream_t stream) {
  const float* P = (const float*)d_in[0];
  const float* T = (const float*)d_in[1];
  const float* W = (const float*)d_in[2];
  float* ws = (float*)d_ws;
  float* out = (float*)d_out;

  hipLaunchKernelGGL(init_ws, dim3(1), dim3(64), 0, stream, ws);
  hipLaunchKernelGGL(prog_loss_main, dim3(GRID), dim3(BLOCK), 0, stream, P, T, W, ws);
  hipLaunchKernelGGL(finalize_k, dim3(1), dim3(1), 0, stream, ws, P, T, out);
}